// Round 1
// baseline (114.324 us; speedup 1.0000x reference)
//
#include <hip/hip_runtime.h>
#include <hip/hip_bf16.h>

#define BB 4
#define TT 2048
#define CC 1024
#define HSZ 64
#define NTOT 8192

typedef __attribute__((ext_vector_type(8))) short bf16x8;
typedef __attribute__((ext_vector_type(4))) float f32x4;

__device__ __forceinline__ unsigned short f2bf(float x) {
    __hip_bfloat16 h = __float2bfloat16(x);
    return *reinterpret_cast<unsigned short*>(&h);
}

// ---- W -> bf16 [192][1024]; q-part pre-scaled by HS^-0.5 ----
__global__ __launch_bounds__(256) void convert_w(
    const float* __restrict__ Wq, const float* __restrict__ Wk,
    const float* __restrict__ Wv, unsigned short* __restrict__ Wh) {
    const int i = blockIdx.x * 256 + threadIdx.x;  // float4 job, 49152 total
    const int c = i >> 8, k4 = (i & 255) * 4;
    float4 wv;
    if (c < 64) {
        wv = *(const float4*)&Wq[(size_t)c * CC + k4];
        wv.x *= 0.125f; wv.y *= 0.125f; wv.z *= 0.125f; wv.w *= 0.125f;
    } else if (c < 128) {
        wv = *(const float4*)&Wk[(size_t)(c - 64) * CC + k4];
    } else {
        wv = *(const float4*)&Wv[(size_t)(c - 128) * CC + k4];
    }
    ushort4 h = {f2bf(wv.x), f2bf(wv.y), f2bf(wv.z), f2bf(wv.w)};
    *(ushort4*)&Wh[(size_t)c * CC + k4] = h;
}

// ---- QKV GEMM: 512 blocks x 256 thr (4 waves), 16 rows/block ----
// x staged bf16 in LDS once (coalesced); per 64-K chunk, W staged coalesced
// from bf16 Wh into LDS; wave w computes n-tiles {3w..3w+2} from LDS fragments.
__global__ __launch_bounds__(256, 2) void qkv_mfma(
    const float* __restrict__ x, const unsigned short* __restrict__ Wh,
    unsigned short* __restrict__ qs, unsigned short* __restrict__ ksb,
    unsigned short* __restrict__ vT) {
    __shared__ __align__(16) unsigned short xs[16 * 1032];  // 33024 B
    __shared__ __align__(16) unsigned short Ws[192 * 72];   // 27648 B
    const int tid = threadIdx.x;
    const int w = tid >> 6, lane = tid & 63;
    const int l16 = lane & 15, quad = lane >> 4;
    const int row0 = blockIdx.x * 16;

    // stage x rows -> bf16 LDS, coalesced
#pragma unroll
    for (int it = 0; it < 16; ++it) {
        float4 xv = *(const float4*)&x[(size_t)(row0 + it) * CC + tid * 4];
        ushort4 h = {f2bf(xv.x), f2bf(xv.y), f2bf(xv.z), f2bf(xv.w)};
        *(ushort4*)&xs[it * 1032 + tid * 4] = h;
    }

    f32x4 acc[3];
#pragma unroll
    for (int i = 0; i < 3; ++i) acc[i] = (f32x4){0.f, 0.f, 0.f, 0.f};

    for (int ch = 0; ch < 16; ++ch) {
        // stage W chunk [192 cols x 64 k] bf16, coalesced (6 x uint4 per thread)
#pragma unroll
        for (int it = 0; it < 6; ++it) {
            const int e = tid + it * 256;          // ushort8 job, 1536 total
            const int c = e >> 3, g = e & 7;
            *(uint4*)&Ws[c * 72 + g * 8] =
                *(const uint4*)&Wh[(size_t)c * CC + ch * 64 + g * 8];
        }
        __syncthreads();
        bf16x8 a0 = *(const bf16x8*)&xs[l16 * 1032 + ch * 64 + quad * 8];
        bf16x8 a1 = *(const bf16x8*)&xs[l16 * 1032 + ch * 64 + 32 + quad * 8];
#pragma unroll
        for (int i = 0; i < 3; ++i) {
            const int t = w * 3 + i;
            bf16x8 b0 = *(const bf16x8*)&Ws[(t * 16 + l16) * 72 + quad * 8];
            bf16x8 b1 = *(const bf16x8*)&Ws[(t * 16 + l16) * 72 + 32 + quad * 8];
            f32x4 a = acc[i];
            a = __builtin_amdgcn_mfma_f32_16x16x32_bf16(a0, b0, a, 0, 0, 0);
            a = __builtin_amdgcn_mfma_f32_16x16x32_bf16(a1, b1, a, 0, 0, 0);
            acc[i] = a;
        }
        __syncthreads();  // Ws reused next chunk
    }

    // epilogue: C rows = quad*4+r, col = t*16+l16 (q scale folded into Wh)
#pragma unroll
    for (int i = 0; i < 3; ++i) {
        const int t = w * 3 + i;
        const int col = t * 16 + l16;
        f32x4 a = acc[i];
        if (t < 4) {
#pragma unroll
            for (int r = 0; r < 4; ++r)
                qs[(size_t)(row0 + quad * 4 + r) * HSZ + col] = f2bf(a[r]);
        } else if (t < 8) {
#pragma unroll
            for (int r = 0; r < 4; ++r)
                ksb[(size_t)(row0 + quad * 4 + r) * HSZ + (col - 64)] = f2bf(a[r]);
        } else {
            ushort4 pk = {f2bf(a[0]), f2bf(a[1]), f2bf(a[2]), f2bf(a[3])};
            *(ushort4*)&vT[(size_t)(col - 128) * NTOT + row0 + quad * 4] = pk;
        }
    }
}

// ---- Flash attention, fixed-max streaming softmax (best-known r6/r10 structure) ----
// R0 change: T5 s_setprio(1) around MFMA clusters (measured +4-7% on attn-class
// kernels with independent waves, learn_hip m191).
__global__ __launch_bounds__(256, 2) void attn_mfma(
    const unsigned short* __restrict__ qs, const unsigned short* __restrict__ ksb,
    const unsigned short* __restrict__ vT, float* __restrict__ out) {
    __shared__ __align__(16) unsigned char smem[17664];
    unsigned short* Ps = (unsigned short*)smem;   // [4][16*72] = 9216 B
    float* Om = (float*)smem;                     // [4][16][68] = 17408 B (after barrier)
    float* Lm = (float*)(smem + 17408);           // [4][16] = 256 B

    const int raw = blockIdx.x;
    const int i = (raw < 256) ? raw : 767 - raw;  // pair long+short causal tiles per CU
    const int b = i >> 7;
    const int qt = i & 127;
    const int t0 = qt * 16;
    const int tid = threadIdx.x;
    const int w = tid >> 6, lane = tid & 63;
    const int l16 = lane & 15, quad = lane >> 4;

    const size_t qoff = (size_t)(b * TT + t0 + l16) * HSZ + quad * 8;
    const bf16x8 aq0 = *(const bf16x8*)&qs[qoff];
    const bf16x8 aq1 = *(const bf16x8*)&qs[qoff + 32];

    f32x4 OC[4];
#pragma unroll
    for (int t = 0; t < 4; ++t) OC[t] = (f32x4){0.f, 0.f, 0.f, 0.f};
    float lsum[4] = {0.f, 0.f, 0.f, 0.f};

    const unsigned short* kbase = ksb + (size_t)b * TT * HSZ;
    const int nk = (qt >> 2) + 1;

    for (int j = w; j < nk; j += 4) {
        const int key0 = j * 64;
        bf16x8 cv0[4], cv1[4];
#pragma unroll
        for (int ht = 0; ht < 4; ++ht) {
            const unsigned short* vp =
                vT + (size_t)(ht * 16 + l16) * NTOT + b * TT + key0 + quad * 8;
            cv0[ht] = *(const bf16x8*)vp;
            cv1[ht] = *(const bf16x8*)(vp + 32);
        }
        f32x4 S[4];
#pragma unroll
        for (int nt = 0; nt < 4; ++nt) {
            const unsigned short* kp =
                kbase + (size_t)(key0 + nt * 16 + l16) * HSZ + quad * 8;
            bf16x8 bk0 = *(const bf16x8*)kp;
            bf16x8 bk1 = *(const bf16x8*)(kp + 32);
            f32x4 a = (f32x4){0.f, 0.f, 0.f, 0.f};
            __builtin_amdgcn_s_setprio(1);
            a = __builtin_amdgcn_mfma_f32_16x16x32_bf16(aq0, bk0, a, 0, 0, 0);
            a = __builtin_amdgcn_mfma_f32_16x16x32_bf16(aq1, bk1, a, 0, 0, 0);
            __builtin_amdgcn_s_setprio(0);
            S[nt] = a;
        }
        if (j == nk - 1) {
#pragma unroll
            for (int nt = 0; nt < 4; ++nt) {
                const int key = key0 + nt * 16 + l16;
#pragma unroll
                for (int r = 0; r < 4; ++r)
                    if (key > t0 + quad * 4 + r) S[nt][r] = -1e30f;
            }
        }
#pragma unroll
        for (int nt = 0; nt < 4; ++nt)
#pragma unroll
            for (int r = 0; r < 4; ++r) S[nt][r] = __expf(S[nt][r]);
#pragma unroll
        for (int r = 0; r < 4; ++r)
            lsum[r] += S[0][r] + S[1][r] + S[2][r] + S[3][r];
        unsigned short* Pw = Ps + w * 1152;
#pragma unroll
        for (int nt = 0; nt < 4; ++nt)
#pragma unroll
            for (int r = 0; r < 4; ++r)
                Pw[(quad * 4 + r) * 72 + nt * 16 + l16] = f2bf(S[nt][r]);
        bf16x8 pf0 = *(const bf16x8*)&Pw[l16 * 72 + quad * 8];
        bf16x8 pf1 = *(const bf16x8*)&Pw[l16 * 72 + 32 + quad * 8];
        __builtin_amdgcn_s_setprio(1);
#pragma unroll
        for (int ht = 0; ht < 4; ++ht) {
            f32x4 a = OC[ht];
            a = __builtin_amdgcn_mfma_f32_16x16x32_bf16(pf0, cv0[ht], a, 0, 0, 0);
            a = __builtin_amdgcn_mfma_f32_16x16x32_bf16(pf1, cv1[ht], a, 0, 0, 0);
            OC[ht] = a;
        }
        __builtin_amdgcn_s_setprio(0);
    }
#pragma unroll
    for (int r = 0; r < 4; ++r) {
        float v = lsum[r];
#pragma unroll
        for (int off = 1; off < 16; off <<= 1) v += __shfl_xor(v, off, 64);
        lsum[r] = v;
    }
    __syncthreads();  // done with Ps; reuse as Om
#pragma unroll
    for (int ht = 0; ht < 4; ++ht)
#pragma unroll
        for (int r = 0; r < 4; ++r)
            Om[(w * 16 + quad * 4 + r) * 68 + ht * 16 + l16] = OC[ht][r];
    if (l16 == 0) {
#pragma unroll
        for (int r = 0; r < 4; ++r) Lm[w * 16 + quad * 4 + r] = lsum[r];
    }
    __syncthreads();
    {
        const int row = tid >> 4, h0 = (tid & 15) * 4;
        float L = 0.f, o0 = 0.f, o1 = 0.f, o2 = 0.f, o3 = 0.f;
#pragma unroll
        for (int w2 = 0; w2 < 4; ++w2) {
            L += Lm[w2 * 16 + row];
            const float* p = &Om[(w2 * 16 + row) * 68 + h0];
            o0 += p[0]; o1 += p[1]; o2 += p[2]; o3 += p[3];
        }
        const float inv = 1.f / L;
        *(float4*)&out[(size_t)(b * TT + t0 + row) * HSZ + h0] =
            (float4){o0 * inv, o1 * inv, o2 * inv, o3 * inv};
    }
}

extern "C" void kernel_launch(void* const* d_in, const int* in_sizes, int n_in,
                              void* d_out, int out_size, void* d_ws, size_t ws_size,
                              hipStream_t stream) {
    const float* x  = (const float*)d_in[0];
    const float* Wq = (const float*)d_in[1];
    const float* Wk = (const float*)d_in[2];
    const float* Wv = (const float*)d_in[3];
    float* out = (float*)d_out;

    unsigned short* qs = (unsigned short*)d_ws;
    unsigned short* ksb = qs + (size_t)NTOT * HSZ;
    unsigned short* vT = ksb + (size_t)NTOT * HSZ;
    unsigned short* Wh = vT + (size_t)NTOT * HSZ;  // 192*1024

    convert_w<<<192, 256, 0, stream>>>(Wq, Wk, Wv, Wh);
    qkv_mfma<<<512, 256, 0, stream>>>(x, Wh, qs, ksb, vT);
    attn_mfma<<<512, 256, 0, stream>>>(qs, ksb, vT, out);
}

// Round 2
// 108.609 us; speedup vs baseline: 1.0526x; 1.0526x over previous
//
#include <hip/hip_runtime.h>
#include <hip/hip_bf16.h>

#define BB 4
#define TT 2048
#define CC 1024
#define HSZ 64
#define NTOT 8192

typedef __attribute__((ext_vector_type(8))) short bf16x8;
typedef __attribute__((ext_vector_type(4))) float f32x4;

__device__ __forceinline__ unsigned short f2bf(float x) {
    __hip_bfloat16 h = __float2bfloat16(x);
    return *reinterpret_cast<unsigned short*>(&h);
}

// ---- W -> bf16 [192][1024]; q-part pre-scaled by HS^-0.5 ----
__global__ __launch_bounds__(256) void convert_w(
    const float* __restrict__ Wq, const float* __restrict__ Wk,
    const float* __restrict__ Wv, unsigned short* __restrict__ Wh) {
    const int i = blockIdx.x * 256 + threadIdx.x;  // float4 job, 49152 total
    const int c = i >> 8, k4 = (i & 255) * 4;
    float4 wv;
    if (c < 64) {
        wv = *(const float4*)&Wq[(size_t)c * CC + k4];
        wv.x *= 0.125f; wv.y *= 0.125f; wv.z *= 0.125f; wv.w *= 0.125f;
    } else if (c < 128) {
        wv = *(const float4*)&Wk[(size_t)(c - 64) * CC + k4];
    } else {
        wv = *(const float4*)&Wv[(size_t)(c - 128) * CC + k4];
    }
    ushort4 h = {f2bf(wv.x), f2bf(wv.y), f2bf(wv.z), f2bf(wv.w)};
    *(ushort4*)&Wh[(size_t)c * CC + k4] = h;
}

// ---- QKV GEMM R1: BM=32 (256 blocks), BN=192, BK=64, 2-phase prefetch ----
// Per chunk: issue next chunk's global loads (x f32 + W bf16) into regs BEFORE
// computing current chunk from LDS; write LDS after barrier. Halves W traffic
// vs BM=16 (98 MB vs 196 MB) and hides global latency under MFMA.
// Wave w owns rows 0..31 x cols [48w,48w+48): acc[2][3] f32x4.
__global__ __launch_bounds__(256) void qkv_mfma(
    const float* __restrict__ x, const unsigned short* __restrict__ Wh,
    unsigned short* __restrict__ qs, unsigned short* __restrict__ ksb,
    unsigned short* __restrict__ vT) {
    __shared__ __align__(16) unsigned short xs[32 * 72];   // 4608 B
    __shared__ __align__(16) unsigned short Ws[192 * 72];  // 27648 B
    const int tid = threadIdx.x;
    const int w = tid >> 6, lane = tid & 63;
    const int l16 = lane & 15, quad = lane >> 4;
    const int row0 = blockIdx.x * 32;

    // staging geometry: x = 32x64 f32 (8 f32/thread); W = 192x64 bf16 (6 ushort8/thread)
    const int xrow = tid >> 3, xcol = (tid & 7) * 8;

    float4 xa, xb;
    uint4 wreg0, wreg1, wreg2, wreg3, wreg4, wreg5;

#define LOADX(ch)                                                            \
    {                                                                        \
        const float* p = &x[(size_t)(row0 + xrow) * CC + (ch) * 64 + xcol];  \
        xa = *(const float4*)p;                                              \
        xb = *(const float4*)(p + 4);                                        \
    }
#define LOADW1(it, dst, ch)                                                  \
    {                                                                        \
        const int e = tid + (it) * 256;                                      \
        const int c = e >> 3, g = e & 7;                                     \
        dst = *(const uint4*)&Wh[(size_t)c * CC + (ch) * 64 + g * 8];        \
    }
#define LOADW(ch)                                                            \
    LOADW1(0, wreg0, ch) LOADW1(1, wreg1, ch) LOADW1(2, wreg2, ch)           \
    LOADW1(3, wreg3, ch) LOADW1(4, wreg4, ch) LOADW1(5, wreg5, ch)
#define STOREW1(it, src)                                                     \
    {                                                                        \
        const int e = tid + (it) * 256;                                      \
        const int c = e >> 3, g = e & 7;                                     \
        *(uint4*)&Ws[c * 72 + g * 8] = src;                                  \
    }
#define WRITELDS()                                                           \
    {                                                                        \
        ushort4 h0 = {f2bf(xa.x), f2bf(xa.y), f2bf(xa.z), f2bf(xa.w)};       \
        ushort4 h1 = {f2bf(xb.x), f2bf(xb.y), f2bf(xb.z), f2bf(xb.w)};       \
        *(ushort4*)&xs[xrow * 72 + xcol] = h0;                               \
        *(ushort4*)&xs[xrow * 72 + xcol + 4] = h1;                           \
        STOREW1(0, wreg0) STOREW1(1, wreg1) STOREW1(2, wreg2)                \
        STOREW1(3, wreg3) STOREW1(4, wreg4) STOREW1(5, wreg5)                \
    }

    f32x4 acc[2][3];
#pragma unroll
    for (int m = 0; m < 2; ++m)
#pragma unroll
        for (int n = 0; n < 3; ++n) acc[m][n] = (f32x4){0.f, 0.f, 0.f, 0.f};

    LOADX(0);
    LOADW(0);
    WRITELDS();
    __syncthreads();

    for (int ch = 0; ch < 16; ++ch) {
        if (ch < 15) {  // prefetch next chunk into registers (latency hidden by MFMA)
            LOADX(ch + 1);
            LOADW(ch + 1);
        }
        bf16x8 am[2][2], bn[3][2];
#pragma unroll
        for (int m = 0; m < 2; ++m)
#pragma unroll
            for (int h = 0; h < 2; ++h)
                am[m][h] = *(const bf16x8*)&xs[(m * 16 + l16) * 72 + h * 32 + quad * 8];
#pragma unroll
        for (int n = 0; n < 3; ++n)
#pragma unroll
            for (int h = 0; h < 2; ++h)
                bn[n][h] =
                    *(const bf16x8*)&Ws[(w * 48 + n * 16 + l16) * 72 + h * 32 + quad * 8];
#pragma unroll
        for (int h = 0; h < 2; ++h)
#pragma unroll
            for (int m = 0; m < 2; ++m)
#pragma unroll
                for (int n = 0; n < 3; ++n)
                    acc[m][n] = __builtin_amdgcn_mfma_f32_16x16x32_bf16(
                        am[m][h], bn[n][h], acc[m][n], 0, 0, 0);
        if (ch < 15) {
            __syncthreads();  // all ds_reads of chunk ch complete
            WRITELDS();       // commit prefetched chunk ch+1
            __syncthreads();  // visible to all waves
        }
    }

    // epilogue: row = row0 + m*16 + quad*4 + r, col = w*48 + n*16 + l16
#pragma unroll
    for (int m = 0; m < 2; ++m) {
#pragma unroll
        for (int n = 0; n < 3; ++n) {
            const int col = w * 48 + n * 16 + l16;
            const int r0 = row0 + m * 16 + quad * 4;
            f32x4 a = acc[m][n];
            if (col < 64) {
#pragma unroll
                for (int r = 0; r < 4; ++r)
                    qs[(size_t)(r0 + r) * HSZ + col] = f2bf(a[r]);
            } else if (col < 128) {
#pragma unroll
                for (int r = 0; r < 4; ++r)
                    ksb[(size_t)(r0 + r) * HSZ + (col - 64)] = f2bf(a[r]);
            } else {
                ushort4 pk = {f2bf(a[0]), f2bf(a[1]), f2bf(a[2]), f2bf(a[3])};
                *(ushort4*)&vT[(size_t)(col - 128) * NTOT + r0] = pk;
            }
        }
    }
#undef LOADX
#undef LOADW1
#undef LOADW
#undef STOREW1
#undef WRITELDS
}

// ---- Flash attention, fixed-max streaming softmax (verified baseline structure) ----
__global__ __launch_bounds__(256, 2) void attn_mfma(
    const unsigned short* __restrict__ qs, const unsigned short* __restrict__ ksb,
    const unsigned short* __restrict__ vT, float* __restrict__ out) {
    __shared__ __align__(16) unsigned char smem[17664];
    unsigned short* Ps = (unsigned short*)smem;   // [4][16*72] = 9216 B
    float* Om = (float*)smem;                     // [4][16][68] = 17408 B (after barrier)
    float* Lm = (float*)(smem + 17408);           // [4][16] = 256 B

    const int raw = blockIdx.x;
    const int i = (raw < 256) ? raw : 767 - raw;  // pair long+short causal tiles per CU
    const int b = i >> 7;
    const int qt = i & 127;
    const int t0 = qt * 16;
    const int tid = threadIdx.x;
    const int w = tid >> 6, lane = tid & 63;
    const int l16 = lane & 15, quad = lane >> 4;

    const size_t qoff = (size_t)(b * TT + t0 + l16) * HSZ + quad * 8;
    const bf16x8 aq0 = *(const bf16x8*)&qs[qoff];
    const bf16x8 aq1 = *(const bf16x8*)&qs[qoff + 32];

    f32x4 OC[4];
#pragma unroll
    for (int t = 0; t < 4; ++t) OC[t] = (f32x4){0.f, 0.f, 0.f, 0.f};
    float lsum[4] = {0.f, 0.f, 0.f, 0.f};

    const unsigned short* kbase = ksb + (size_t)b * TT * HSZ;
    const int nk = (qt >> 2) + 1;

    for (int j = w; j < nk; j += 4) {
        const int key0 = j * 64;
        bf16x8 cv0[4], cv1[4];
#pragma unroll
        for (int ht = 0; ht < 4; ++ht) {
            const unsigned short* vp =
                vT + (size_t)(ht * 16 + l16) * NTOT + b * TT + key0 + quad * 8;
            cv0[ht] = *(const bf16x8*)vp;
            cv1[ht] = *(const bf16x8*)(vp + 32);
        }
        f32x4 S[4];
#pragma unroll
        for (int nt = 0; nt < 4; ++nt) {
            const unsigned short* kp =
                kbase + (size_t)(key0 + nt * 16 + l16) * HSZ + quad * 8;
            bf16x8 bk0 = *(const bf16x8*)kp;
            bf16x8 bk1 = *(const bf16x8*)(kp + 32);
            f32x4 a = (f32x4){0.f, 0.f, 0.f, 0.f};
            a = __builtin_amdgcn_mfma_f32_16x16x32_bf16(aq0, bk0, a, 0, 0, 0);
            a = __builtin_amdgcn_mfma_f32_16x16x32_bf16(aq1, bk1, a, 0, 0, 0);
            S[nt] = a;
        }
        if (j == nk - 1) {
#pragma unroll
            for (int nt = 0; nt < 4; ++nt) {
                const int key = key0 + nt * 16 + l16;
#pragma unroll
                for (int r = 0; r < 4; ++r)
                    if (key > t0 + quad * 4 + r) S[nt][r] = -1e30f;
            }
        }
#pragma unroll
        for (int nt = 0; nt < 4; ++nt)
#pragma unroll
            for (int r = 0; r < 4; ++r) S[nt][r] = __expf(S[nt][r]);
#pragma unroll
        for (int r = 0; r < 4; ++r)
            lsum[r] += S[0][r] + S[1][r] + S[2][r] + S[3][r];
        unsigned short* Pw = Ps + w * 1152;
#pragma unroll
        for (int nt = 0; nt < 4; ++nt)
#pragma unroll
            for (int r = 0; r < 4; ++r)
                Pw[(quad * 4 + r) * 72 + nt * 16 + l16] = f2bf(S[nt][r]);
        bf16x8 pf0 = *(const bf16x8*)&Pw[l16 * 72 + quad * 8];
        bf16x8 pf1 = *(const bf16x8*)&Pw[l16 * 72 + 32 + quad * 8];
#pragma unroll
        for (int ht = 0; ht < 4; ++ht) {
            f32x4 a = OC[ht];
            a = __builtin_amdgcn_mfma_f32_16x16x32_bf16(pf0, cv0[ht], a, 0, 0, 0);
            a = __builtin_amdgcn_mfma_f32_16x16x32_bf16(pf1, cv1[ht], a, 0, 0, 0);
            OC[ht] = a;
        }
    }
#pragma unroll
    for (int r = 0; r < 4; ++r) {
        float v = lsum[r];
#pragma unroll
        for (int off = 1; off < 16; off <<= 1) v += __shfl_xor(v, off, 64);
        lsum[r] = v;
    }
    __syncthreads();  // done with Ps; reuse as Om
#pragma unroll
    for (int ht = 0; ht < 4; ++ht)
#pragma unroll
        for (int r = 0; r < 4; ++r)
            Om[(w * 16 + quad * 4 + r) * 68 + ht * 16 + l16] = OC[ht][r];
    if (l16 == 0) {
#pragma unroll
        for (int r = 0; r < 4; ++r) Lm[w * 16 + quad * 4 + r] = lsum[r];
    }
    __syncthreads();
    {
        const int row = tid >> 4, h0 = (tid & 15) * 4;
        float L = 0.f, o0 = 0.f, o1 = 0.f, o2 = 0.f, o3 = 0.f;
#pragma unroll
        for (int w2 = 0; w2 < 4; ++w2) {
            L += Lm[w2 * 16 + row];
            const float* p = &Om[(w2 * 16 + row) * 68 + h0];
            o0 += p[0]; o1 += p[1]; o2 += p[2]; o3 += p[3];
        }
        const float inv = 1.f / L;
        *(float4*)&out[(size_t)(b * TT + t0 + row) * HSZ + h0] =
            (float4){o0 * inv, o1 * inv, o2 * inv, o3 * inv};
    }
}

extern "C" void kernel_launch(void* const* d_in, const int* in_sizes, int n_in,
                              void* d_out, int out_size, void* d_ws, size_t ws_size,
                              hipStream_t stream) {
    const float* x  = (const float*)d_in[0];
    const float* Wq = (const float*)d_in[1];
    const float* Wk = (const float*)d_in[2];
    const float* Wv = (const float*)d_in[3];
    float* out = (float*)d_out;

    unsigned short* qs = (unsigned short*)d_ws;
    unsigned short* ksb = qs + (size_t)NTOT * HSZ;
    unsigned short* vT = ksb + (size_t)NTOT * HSZ;
    unsigned short* Wh = vT + (size_t)NTOT * HSZ;  // 192*1024

    convert_w<<<192, 256, 0, stream>>>(Wq, Wk, Wv, Wh);
    qkv_mfma<<<256, 256, 0, stream>>>(x, Wh, qs, ksb, vT);
    attn_mfma<<<512, 256, 0, stream>>>(qs, ksb, vT, out);
}